// Round 1
// baseline (609.264 us; speedup 1.0000x reference)
//
#include <hip/hip_runtime.h>
#include <math.h>

#define NB 4
#define NC 128
#define NH 96
#define NW 128
#define HW (NH*NW)            // 12288
#define NS 1024
#define SCALE_F 20.0f
#define THRESH_F 0.9995f

#define S_TILE 16
#define BLOCK 256
#define PX_PER_THREAD 4
#define PX_TILE (BLOCK*PX_PER_THREAD)   // 1024
#define N_PXT (HW/PX_TILE)              // 12
#define N_ST (NS/S_TILE)                // 64

// ---------------------------------------------------------------------------
// Kernel A: gather sampled query vectors samp[b][s][c] = src[b][c][loc[b][s]]
// and zero the per-(b,s) sum accumulators.
// ---------------------------------------------------------------------------
__global__ __launch_bounds__(256) void gather_kernel(
    const float* __restrict__ src, const int* __restrict__ loc,
    float* __restrict__ samp, float* __restrict__ sums)
{
    int idx = blockIdx.x * 256 + threadIdx.x;
    if (idx < NB * NS) sums[idx] = 0.0f;
    if (idx < NB * NS * NC) {
        int c  = idx & (NC - 1);
        int bs = idx >> 7;          // b*NS + s
        int b  = bs >> 10;
        int l  = loc[bs];
        samp[idx] = src[((size_t)(b * NC + c)) * HW + l];
    }
}

// ---------------------------------------------------------------------------
// Kernel B: corr = samp · tgt  (per-batch GEMM), fused exp/mask, write
// unnormalized response, accumulate per-(b,s) sums via wave-reduced atomics.
// Block: 256 threads, tile = S_TILE(16) s-values x 1024 contiguous pixels.
// Each thread: 4 pixels (float4), 16 s -> 64 fp32 accumulators.
// ---------------------------------------------------------------------------
__global__ __launch_bounds__(256) void corr_kernel(
    const float* __restrict__ tgt, const float* __restrict__ samp,
    const float* __restrict__ mask, float* __restrict__ out,
    float* __restrict__ sums)
{
    const int b  = blockIdx.z;
    const int st = blockIdx.y;      // s-tile index, 0..63
    const int pt = blockIdx.x;      // pixel-tile index, 0..11
    const int tid = threadIdx.x;

    __shared__ float smp[S_TILE * NC];   // 8 KB

    // Stage the 16x128 samp tile (2048 floats = 512 float4) coalesced.
    {
        const float4* g = (const float4*)(samp + ((size_t)(b * NS + st * S_TILE)) * NC);
        float4* s4 = (float4*)smp;
        s4[tid]       = g[tid];
        s4[tid + 256] = g[tid + 256];
    }
    __syncthreads();

    const int px = pt * PX_TILE + tid * 4;
    const float* tb = tgt + (size_t)b * NC * HW + px;

    float4 acc[S_TILE];
#pragma unroll
    for (int s = 0; s < S_TILE; ++s) acc[s] = make_float4(0.f, 0.f, 0.f, 0.f);

    for (int c = 0; c < NC; c += 4) {
        const float4 t0 = *(const float4*)(tb + (size_t)(c + 0) * HW);
        const float4 t1 = *(const float4*)(tb + (size_t)(c + 1) * HW);
        const float4 t2 = *(const float4*)(tb + (size_t)(c + 2) * HW);
        const float4 t3 = *(const float4*)(tb + (size_t)(c + 3) * HW);
#pragma unroll
        for (int s = 0; s < S_TILE; ++s) {
            const float4 sa = *(const float4*)&smp[s * NC + c];  // ds_read_b128, broadcast
            acc[s].x = fmaf(sa.x, t0.x, fmaf(sa.y, t1.x, fmaf(sa.z, t2.x, fmaf(sa.w, t3.x, acc[s].x))));
            acc[s].y = fmaf(sa.x, t0.y, fmaf(sa.y, t1.y, fmaf(sa.z, t2.y, fmaf(sa.w, t3.y, acc[s].y))));
            acc[s].z = fmaf(sa.x, t0.z, fmaf(sa.y, t1.z, fmaf(sa.z, t2.z, fmaf(sa.w, t3.z, acc[s].z))));
            acc[s].w = fmaf(sa.x, t0.w, fmaf(sa.y, t1.w, fmaf(sa.z, t2.w, fmaf(sa.w, t3.w, acc[s].w))));
        }
    }

    // Epilogue: exp / mask / store / per-s row-sum.
    const float4 mv = *(const float4*)(mask + (size_t)b * HW + px);
    const int lane = tid & 63;

#pragma unroll
    for (int s = 0; s < S_TILE; ++s) {
        float4 r;
        {
            float a;
            a = 0.5f * acc[s].x + 0.5f - THRESH_F; r.x = __expf(SCALE_F * a) * mv.x;
            a = 0.5f * acc[s].y + 0.5f - THRESH_F; r.y = __expf(SCALE_F * a) * mv.y;
            a = 0.5f * acc[s].z + 0.5f - THRESH_F; r.z = __expf(SCALE_F * a) * mv.z;
            a = 0.5f * acc[s].w + 0.5f - THRESH_F; r.w = __expf(SCALE_F * a) * mv.w;
        }
        const int srow = b * NS + st * S_TILE + s;
        *(float4*)(out + (size_t)srow * HW + px) = r;

        float v = (r.x + r.y) + (r.z + r.w);
#pragma unroll
        for (int o = 32; o > 0; o >>= 1) v += __shfl_down(v, o, 64);
        if (lane == 0) atomicAdd(&sums[srow], v);
    }
}

// ---------------------------------------------------------------------------
// Kernel C: normalize each (b,s) row by its sum.
// ---------------------------------------------------------------------------
__global__ __launch_bounds__(256) void norm_kernel(
    float* __restrict__ out, const float* __restrict__ sums)
{
    const int b = blockIdx.z;
    const int s = blockIdx.y;
    const int pt = blockIdx.x;
    const float inv = 1.0f / sums[b * NS + s];
    const int px = pt * PX_TILE + threadIdx.x * 4;
    float4* p = (float4*)(out + ((size_t)(b * NS + s)) * HW + px);
    float4 v = *p;
    v.x *= inv; v.y *= inv; v.z *= inv; v.w *= inv;
    *p = v;
}

extern "C" void kernel_launch(void* const* d_in, const int* in_sizes, int n_in,
                              void* d_out, int out_size, void* d_ws, size_t ws_size,
                              hipStream_t stream) {
    const float* src  = (const float*)d_in[0];
    const float* tgt  = (const float*)d_in[1];
    const int*   loc  = (const int*)d_in[2];
    const float* mask = (const float*)d_in[3];
    float* out = (float*)d_out;

    float* samp = (float*)d_ws;                                   // NB*NS*NC fp32 = 2 MB
    float* sums = (float*)((char*)d_ws + (size_t)NB * NS * NC * sizeof(float)); // 16 KB

    gather_kernel<<<dim3((NB * NS * NC) / 256), 256, 0, stream>>>(src, loc, samp, sums);

    dim3 gB(N_PXT, N_ST, NB);   // (12, 64, 4)
    corr_kernel<<<gB, BLOCK, 0, stream>>>(tgt, samp, mask, out, sums);

    dim3 gC(N_PXT, NS, NB);     // (12, 1024, 4)
    norm_kernel<<<gC, BLOCK, 0, stream>>>(out, sums);
}

// Round 2
// 359.970 us; speedup vs baseline: 1.6925x; 1.6925x over previous
//
#include <hip/hip_runtime.h>

typedef unsigned int u32;
typedef unsigned short u16;
typedef short s8v __attribute__((ext_vector_type(8)));     // 8 bf16 = 4 VGPR
typedef float f16v __attribute__((ext_vector_type(16)));   // 32x32 accumulator

#define NB 4
#define NC 128
#define HW 12288
#define NS 1024

// resp = exp(20*(0.5*corr + 0.5 - 0.9995)) = exp(10*corr - 9.99)
#define EXP_A 10.0f
#define EXP_B (-9.99f)

__device__ inline u16 f2bf(float f) {            // round-to-nearest-even fp32->bf16
    u32 u = __float_as_uint(f);
    u32 r = u + 0x7fffu + ((u >> 16) & 1u);
    return (u16)(r >> 16);
}
__device__ inline float bf2f(u16 h) { return __uint_as_float(((u32)h) << 16); }

// ---------------------------------------------------------------------------
// prep_samp: gather sampled vectors, split into bf16 hi/lo planes, zero sums.
// One 256-thread block handles 2 (b,s) rows; lane = channel (writes coalesced).
// ---------------------------------------------------------------------------
__global__ __launch_bounds__(256) void prep_samp(
    const float* __restrict__ src, const int* __restrict__ loc,
    u16* __restrict__ shi, u16* __restrict__ slo, float* __restrict__ sums)
{
    int t = threadIdx.x;
    int gid = blockIdx.x * 256 + t;
    if (gid < NB * NS) sums[gid] = 0.0f;
    int bs = blockIdx.x * 2 + (t >> 7);
    int c  = t & 127;
    int b  = bs >> 10;
    int l  = loc[bs];
    float v = src[((size_t)(b * NC + c)) * HW + l];
    u16 h  = f2bf(v);
    u16 lo = f2bf(v - bf2f(h));
    shi[bs * NC + c] = h;
    slo[bs * NC + c] = lo;
}

// ---------------------------------------------------------------------------
// prep_tgt: transpose tgt [b][c][px] fp32 -> B2t [b*HW + px][c] bf16 hi/lo.
// Block handles 64 px x 128 c via padded LDS tile.
// ---------------------------------------------------------------------------
__global__ __launch_bounds__(256) void prep_tgt(
    const float* __restrict__ tgt, u16* __restrict__ bhi, u16* __restrict__ blo)
{
    __shared__ float tile[NC][65];
    int b = blockIdx.y, pt = blockIdx.x, t = threadIdx.x;
    const float* src = tgt + ((size_t)b * NC) * HW + pt * 64;
#pragma unroll
    for (int it = 0; it < 32; ++it) {
        int idx = it * 256 + t;
        int c = idx >> 6, px = idx & 63;
        tile[c][px] = src[(size_t)c * HW + px];
    }
    __syncthreads();
    int px = t >> 2, cq = (t & 3) * 32;
    u32 hw_[16], lw_[16];
#pragma unroll
    for (int k = 0; k < 16; ++k) {
        float v0 = tile[cq + 2 * k][px], v1 = tile[cq + 2 * k + 1][px];
        u16 h0 = f2bf(v0), h1 = f2bf(v1);
        u16 l0 = f2bf(v0 - bf2f(h0)), l1 = f2bf(v1 - bf2f(h1));
        hw_[k] = (u32)h0 | ((u32)h1 << 16);
        lw_[k] = (u32)l0 | ((u32)l1 << 16);
    }
    size_t rowbase = ((size_t)b * HW + pt * 64 + px) * NC + cq;  // u16 elems
    uint4* ph = (uint4*)(bhi + rowbase);
    uint4* pl = (uint4*)(blo + rowbase);
#pragma unroll
    for (int q = 0; q < 4; ++q) {
        ph[q] = make_uint4(hw_[4*q], hw_[4*q+1], hw_[4*q+2], hw_[4*q+3]);
        pl[q] = make_uint4(lw_[4*q], lw_[4*q+1], lw_[4*q+2], lw_[4*q+3]);
    }
}

// ---------------------------------------------------------------------------
// corr_mfma<DO_STORE>: split-bf16 MFMA GEMM, fused exp/mask epilogue.
// Block tile: 256 s x 64 px; 4 waves, wave w = s rows [w*64, w*64+64).
// Wave tile: 2x2 blocks of 32x32 (v_mfma_f32_32x32x16_bf16), K=128, 3 passes.
// DO_STORE=0: accumulate row sums (LDS reduce + 1 atomic/row), no store.
// DO_STORE=1: recompute, scale by 1/sum, store final output.
// ---------------------------------------------------------------------------
template <int DO_STORE>
__global__ __launch_bounds__(256) void corr_mfma(
    const u16* __restrict__ bhi, const u16* __restrict__ blo,
    const u16* __restrict__ shi, const u16* __restrict__ slo,
    const float* __restrict__ mask, float* __restrict__ sums,
    float* __restrict__ out)
{
    __shared__ char smem[33792];           // B tiles (32 KB) / row-sum scratch (33 KB)
    __shared__ float inv[256];
    u16*   Bt = (u16*)smem;                // [plane 2][px 64 * NC], kg-chunks XOR-swizzled
    float* rs = (float*)smem;              // [row 256][33]

    const int b = blockIdx.z, st = blockIdx.y, pt = blockIdx.x;
    const int t = threadIdx.x, w = t >> 6, l = t & 63;
    const int h = l >> 5, ln = l & 31;

    // Stage B tile: 64 px x 128 c, hi+lo planes, swizzle kg ^= (px & 7).
    {
        const u16* g0 = bhi + ((size_t)b * HW + pt * 64) * NC;
        const u16* g1 = blo + ((size_t)b * HW + pt * 64) * NC;
#pragma unroll
        for (int p = 0; p < 2; ++p) {
            const u16* gs = p ? g1 : g0;
#pragma unroll
            for (int it = 0; it < 4; ++it) {
                int g = it * 256 + t;              // 16B chunk index 0..1023
                int px = g >> 4, kg = g & 15;
                uint4 v = *(const uint4*)(gs + g * 8);
                int swz = (kg & 8) | ((kg ^ px) & 7);
                *(uint4*)&Bt[p * 64 * NC + px * NC + swz * 8] = v;
            }
        }
    }
    if (DO_STORE) {
        inv[t] = 1.0f / sums[b * NS + st * 256 + t];
    }
    __syncthreads();

    f16v acc[2][2];
#pragma unroll
    for (int i = 0; i < 2; ++i)
#pragma unroll
        for (int j = 0; j < 2; ++j)
#pragma unroll
            for (int r = 0; r < 16; ++r) acc[i][j][r] = 0.0f;

    // A rows: srow0 + i*32 ; lane holds A[m=ln][k = kk*16 + h*8 + j]
    const int srow0 = st * 256 + w * 64 + ln;
    const u16* ah = shi + ((size_t)(b * NS) + srow0) * NC + h * 8;
    const u16* al = slo + ((size_t)(b * NS) + srow0) * NC + h * 8;

#pragma unroll
    for (int kk = 0; kk < 8; ++kk) {
        s8v a_hi[2], a_lo[2], b_hi[2], b_lo[2];
#pragma unroll
        for (int i = 0; i < 2; ++i) {
            a_hi[i] = *(const s8v*)(ah + i * 32 * NC + kk * 16);
            a_lo[i] = *(const s8v*)(al + i * 32 * NC + kk * 16);
        }
        int kg = kk * 2 + h;
#pragma unroll
        for (int j = 0; j < 2; ++j) {
            int px = j * 32 + ln;
            int swz = (kg & 8) | ((kg ^ px) & 7);
            b_hi[j] = *(const s8v*)&Bt[0 * 64 * NC + px * NC + swz * 8];
            b_lo[j] = *(const s8v*)&Bt[1 * 64 * NC + px * NC + swz * 8];
        }
#pragma unroll
        for (int i = 0; i < 2; ++i)
#pragma unroll
            for (int j = 0; j < 2; ++j) {
                acc[i][j] = __builtin_amdgcn_mfma_f32_32x32x16_bf16(a_hi[i], b_hi[j], acc[i][j], 0, 0, 0);
                acc[i][j] = __builtin_amdgcn_mfma_f32_32x32x16_bf16(a_lo[i], b_hi[j], acc[i][j], 0, 0, 0);
                acc[i][j] = __builtin_amdgcn_mfma_f32_32x32x16_bf16(a_hi[i], b_lo[j], acc[i][j], 0, 0, 0);
            }
    }

    // Epilogue. C/D layout: col = ln (px), row = (r&3) + 8*(r>>2) + 4*h.
    float mv[2];
#pragma unroll
    for (int j = 0; j < 2; ++j) mv[j] = mask[(size_t)b * HW + pt * 64 + j * 32 + ln];

    if (DO_STORE) {
#pragma unroll
        for (int i = 0; i < 2; ++i) {
            int rbase = w * 64 + i * 32 + 4 * h;
#pragma unroll
            for (int j = 0; j < 2; ++j) {
                float* obase = out + ((size_t)(b * NS) + st * 256) * HW + (size_t)pt * 64 + j * 32 + ln;
#pragma unroll
                for (int r = 0; r < 16; ++r) {
                    int row = rbase + (r & 3) + 8 * (r >> 2);
                    float e = __expf(fmaf(acc[i][j][r], EXP_A, EXP_B)) * mv[j];
                    obase[(size_t)row * HW] = e * inv[row];
                }
            }
        }
    } else {
        __syncthreads();   // all waves done reading Bt; reuse smem as rs
#pragma unroll
        for (int i = 0; i < 2; ++i) {
            int rbase = w * 64 + i * 32 + 4 * h;
#pragma unroll
            for (int r = 0; r < 16; ++r) {
                int row = rbase + (r & 3) + 8 * (r >> 2);
                float e0 = __expf(fmaf(acc[i][0][r], EXP_A, EXP_B)) * mv[0];
                float e1 = __expf(fmaf(acc[i][1][r], EXP_A, EXP_B)) * mv[1];
                rs[row * 33 + ln] = e0 + e1;       // conflict-free (33 stride)
            }
        }
        __syncthreads();
        float tot = 0.0f;
#pragma unroll
        for (int c = 0; c < 32; ++c) tot += rs[t * 33 + c];
        atomicAdd(&sums[b * NS + st * 256 + t], tot);
    }
}

extern "C" void kernel_launch(void* const* d_in, const int* in_sizes, int n_in,
                              void* d_out, int out_size, void* d_ws, size_t ws_size,
                              hipStream_t stream) {
    const float* src  = (const float*)d_in[0];
    const float* tgt  = (const float*)d_in[1];
    const int*   loc  = (const int*)d_in[2];
    const float* mask = (const float*)d_in[3];
    float* out = (float*)d_out;

    char* ws = (char*)d_ws;
    const size_t PLANE = (size_t)NB * HW * NC * sizeof(u16);   // 12,582,912
    const size_t SPLANE = (size_t)NB * NS * NC * sizeof(u16);  //  1,048,576
    u16* bhi = (u16*)ws;
    u16* blo = (u16*)(ws + PLANE);
    u16* shi = (u16*)(ws + 2 * PLANE);
    u16* slo = (u16*)(ws + 2 * PLANE + SPLANE);
    float* sums = (float*)(ws + 2 * PLANE + 2 * SPLANE);       // 16 KB

    prep_samp<<<dim3(NB * NS / 2), 256, 0, stream>>>(src, loc, shi, slo, sums);
    prep_tgt<<<dim3(HW / 64, NB), 256, 0, stream>>>(tgt, bhi, blo);

    dim3 g(HW / 64, NS / 256, NB);   // (192, 4, 4)
    corr_mfma<0><<<g, 256, 0, stream>>>(bhi, blo, shi, slo, mask, sums, out);
    corr_mfma<1><<<g, 256, 0, stream>>>(bhi, blo, shi, slo, mask, sums, out);
}

// Round 3
// 323.460 us; speedup vs baseline: 1.8836x; 1.1129x over previous
//
#include <hip/hip_runtime.h>

typedef unsigned int u32;
typedef unsigned short u16;
typedef short s8v __attribute__((ext_vector_type(8)));     // 8 bf16 = 4 VGPR
typedef float f16v __attribute__((ext_vector_type(16)));   // 32x32 accumulator

#define NB 4
#define NC 128
#define HW 12288
#define NS 1024

// resp = exp(20*(0.5*corr + 0.5 - 0.9995)) = exp(10*corr - 9.99)
#define EXP_A 10.0f
#define EXP_B (-9.99f)

#define TS 256            // s-tile per block
#define TP 256            // px-tile per block
#define NPT (HW/TP)       // 48
#define NST (NS/TS)       // 4

__device__ inline u16 f2bf(float f) {            // RNE fp32->bf16
    u32 u = __float_as_uint(f);
    return (u16)((u + 0x7fffu + ((u >> 16) & 1u)) >> 16);
}
__device__ inline float bf2f(u16 h) { return __uint_as_float(((u32)h) << 16); }

__device__ inline void gload_lds16(const void* g, void* l) {
    __builtin_amdgcn_global_load_lds(
        (const __attribute__((address_space(1))) void*)g,
        (__attribute__((address_space(3))) void*)l, 16, 0, 0);
}

// ---------------------------------------------------------------------------
// prep_samp: gather sampled vectors -> As[b][kc][s][slot][8] bf16 hi/lo,
// slot = u ^ ((s>>1)&3) bank swizzle baked into the layout. Also zero sums.
// ---------------------------------------------------------------------------
__global__ __launch_bounds__(256) void prep_samp(
    const float* __restrict__ src, const int* __restrict__ loc,
    u16* __restrict__ ahi, u16* __restrict__ alo, float* __restrict__ sums)
{
    int t = threadIdx.x;
    int gid = blockIdx.x * 256 + t;
    if (gid < NB * NS) sums[gid] = 0.0f;
    int bs = blockIdx.x * 2 + (t >> 7);
    int c  = t & 127;
    int b  = bs >> 10, s = bs & 1023;
    int l  = loc[bs];
    float v = src[((size_t)(b * NC + c)) * HW + l];
    u16 h  = f2bf(v);
    u16 lo = f2bf(v - bf2f(h));
    int kc = c >> 5, u = (c >> 3) & 3, e = c & 7;
    int slot = u ^ ((s >> 1) & 3);
    size_t off = ((size_t)((b * 4 + kc) * NS + s)) * 32 + slot * 8 + e;
    ahi[off] = h;
    alo[off] = lo;
}

// ---------------------------------------------------------------------------
// prep_tgt: tgt [b][c][px] fp32 -> Bq[b][kc][px][slot][8] bf16 hi/lo.
// No LDS needed: reads are coalesced per-c (lane = px), writes are 16B units.
// ---------------------------------------------------------------------------
__global__ __launch_bounds__(256) void prep_tgt(
    const float* __restrict__ tgt, u16* __restrict__ bhi, u16* __restrict__ blo)
{
    int b = blockIdx.y, pt = blockIdx.x, t = threadIdx.x;
    int pxl = t & 63, u = t >> 6;
    int px = pt * 64 + pxl;
    int slot = u ^ ((px >> 1) & 3);
#pragma unroll
    for (int kc = 0; kc < 4; ++kc) {
        int c0 = kc * 32 + u * 8;
        u32 hq[4], lq[4];
#pragma unroll
        for (int k = 0; k < 4; ++k) {
            float v0 = tgt[((size_t)(b * NC + c0 + 2 * k)) * HW + px];
            float v1 = tgt[((size_t)(b * NC + c0 + 2 * k + 1)) * HW + px];
            u16 h0 = f2bf(v0), h1 = f2bf(v1);
            u16 l0 = f2bf(v0 - bf2f(h0)), l1 = f2bf(v1 - bf2f(h1));
            hq[k] = (u32)h0 | ((u32)h1 << 16);
            lq[k] = (u32)l0 | ((u32)l1 << 16);
        }
        size_t off = (((size_t)((b * 4 + kc) * HW + px)) * 4 + slot) * 8;  // u16 units
        *(uint4*)(bhi + off) = make_uint4(hq[0], hq[1], hq[2], hq[3]);
        *(uint4*)(blo + off) = make_uint4(lq[0], lq[1], lq[2], lq[3]);
    }
}

// ---------------------------------------------------------------------------
// corr2<DO_STORE>: split-bf16 MFMA GEMM, 256s x 256px block tile, 8 waves.
// K chunked by 32; A+B hi/lo staged to LDS (64 KB) via global_load_lds w=16.
// XCD swizzle: blocks sharing a B-tile (same pt,b; st=0..3) get ids 8 apart.
// DO_STORE=0: row sums via LDS scratch + 1 atomic per (row,half).
// DO_STORE=1: recompute, scale by 1/sum, store.
// ---------------------------------------------------------------------------
template <int DO_STORE>
__global__ __launch_bounds__(512) void corr2(
    const u16* __restrict__ bhi, const u16* __restrict__ blo,
    const u16* __restrict__ ahi, const u16* __restrict__ alo,
    const float* __restrict__ mask, float* __restrict__ sums,
    float* __restrict__ out)
{
    __shared__ __align__(1024) char sm[65536];   // [rg 4][row 256][slot 4][16B]
    __shared__ float inv[TS];

    // Decode block id with XCD-aware swizzle (xcd = id & 7 heuristic).
    int f = blockIdx.x;
    int xcd = f & 7, r0 = f >> 3;          // r0: 0..95
    int st = r0 & 3;
    int p  = (r0 >> 2) * 8 + xcd;          // 0..191
    int b  = p / 48, pt = p - b * 48;      // pt: 0..47

    int t = threadIdx.x, w = t >> 6, l = t & 63, ln = l & 31, h = l >> 5;
    int ws = w >> 1, wp = w & 1;

    if (DO_STORE) {
        if (t < TS) inv[t] = 1.0f / sums[b * NS + st * TS + t];
    }

    f16v acc[2][4];
#pragma unroll
    for (int i = 0; i < 2; ++i)
#pragma unroll
        for (int j = 0; j < 4; ++j)
#pragma unroll
            for (int r = 0; r < 16; ++r) acc[i][j][r] = 0.0f;

    for (int kc = 0; kc < 4; ++kc) {
        const char* ga_h = (const char*)ahi + ((size_t)((b * 4 + kc) * NS + st * TS)) * 64;
        const char* ga_l = (const char*)alo + ((size_t)((b * 4 + kc) * NS + st * TS)) * 64;
        const char* gb_h = (const char*)bhi + ((size_t)((b * 4 + kc) * HW + pt * TP)) * 64;
        const char* gb_l = (const char*)blo + ((size_t)((b * 4 + kc) * HW + pt * TP)) * 64;
        // Stage 4 x 16 KB regions; 64 wave-chunks of 1 KB, 8 per wave.
#pragma unroll
        for (int it = 0; it < 8; ++it) {
            int q = w * 8 + it;                // wave-uniform
            int rg = q >> 4, inner = q & 15;
            const char* gb = rg == 0 ? ga_h : rg == 1 ? ga_l : rg == 2 ? gb_h : gb_l;
            gload_lds16(gb + inner * 1024 + l * 16, sm + q * 1024);
        }
        __syncthreads();

#pragma unroll
        for (int kk2 = 0; kk2 < 2; ++kk2) {
            int u = kk2 * 2 + h;               // 16B unit within 32-k chunk
            s8v a_h[2], a_l[2], b_h[4], b_l[4];
#pragma unroll
            for (int i = 0; i < 2; ++i) {
                int row = ws * 64 + i * 32 + ln;
                int sl = u ^ ((row >> 1) & 3);
                a_h[i] = *(const s8v*)(sm + 0 * 16384 + row * 64 + sl * 16);
                a_l[i] = *(const s8v*)(sm + 1 * 16384 + row * 64 + sl * 16);
            }
#pragma unroll
            for (int j = 0; j < 4; ++j) {
                int px = wp * 128 + j * 32 + ln;
                int sl = u ^ ((px >> 1) & 3);
                b_h[j] = *(const s8v*)(sm + 2 * 16384 + px * 64 + sl * 16);
                b_l[j] = *(const s8v*)(sm + 3 * 16384 + px * 64 + sl * 16);
            }
#pragma unroll
            for (int i = 0; i < 2; ++i)
#pragma unroll
                for (int j = 0; j < 4; ++j) {
                    acc[i][j] = __builtin_amdgcn_mfma_f32_32x32x16_bf16(a_h[i], b_h[j], acc[i][j], 0, 0, 0);
                    acc[i][j] = __builtin_amdgcn_mfma_f32_32x32x16_bf16(a_l[i], b_h[j], acc[i][j], 0, 0, 0);
                    acc[i][j] = __builtin_amdgcn_mfma_f32_32x32x16_bf16(a_h[i], b_l[j], acc[i][j], 0, 0, 0);
                }
        }
        __syncthreads();   // protect sm before next chunk / epilogue reuse
    }

    // Epilogue. C/D layout: col = ln (px), row_local = (r&3) + 8*(r>>2) + 4*h.
    float mv[4];
#pragma unroll
    for (int j = 0; j < 4; ++j)
        mv[j] = mask[(size_t)b * HW + pt * TP + wp * 128 + j * 32 + ln];

    if (DO_STORE) {
        float* ob0 = out + ((size_t)(b * NS + st * TS)) * HW + pt * TP + wp * 128 + ln;
#pragma unroll
        for (int i = 0; i < 2; ++i) {
            int rb = ws * 64 + i * 32 + 4 * h;
#pragma unroll
            for (int j = 0; j < 4; ++j) {
#pragma unroll
                for (int r = 0; r < 16; ++r) {
                    int row = rb + (r & 3) + 8 * (r >> 2);
                    float e = __expf(fmaf(acc[i][j][r], EXP_A, EXP_B)) * mv[j];
                    ob0[(size_t)row * HW + j * 32] = e * inv[row];
                }
            }
        }
    } else {
        float* rs = (float*)sm;     // [wp 2][row 256][ln 32] = 64 KB exactly
#pragma unroll
        for (int i = 0; i < 2; ++i) {
            int rb = ws * 64 + i * 32 + 4 * h;
#pragma unroll
            for (int r = 0; r < 16; ++r) {
                int row = rb + (r & 3) + 8 * (r >> 2);
                float e = 0.0f;
#pragma unroll
                for (int j = 0; j < 4; ++j)
                    e += __expf(fmaf(acc[i][j][r], EXP_A, EXP_B)) * mv[j];
                rs[(wp * TS + row) * 32 + ln] = e;
            }
        }
        __syncthreads();
        int row = t & 255, half = t >> 8;
        float tot = 0.0f;
#pragma unroll
        for (int c = 0; c < 32; ++c)
            tot += rs[(half * TS + row) * 32 + ((c + t) & 31)];  // rotated: no bank conflict
        atomicAdd(&sums[b * NS + st * TS + row], tot);
    }
}

extern "C" void kernel_launch(void* const* d_in, const int* in_sizes, int n_in,
                              void* d_out, int out_size, void* d_ws, size_t ws_size,
                              hipStream_t stream) {
    const float* src  = (const float*)d_in[0];
    const float* tgt  = (const float*)d_in[1];
    const int*   loc  = (const int*)d_in[2];
    const float* mask = (const float*)d_in[3];
    float* out = (float*)d_out;

    char* ws = (char*)d_ws;
    const size_t BPLANE = (size_t)NB * 4 * HW * 32 * sizeof(u16);  // 12.58 MB
    const size_t APLANE = (size_t)NB * 4 * NS * 32 * sizeof(u16);  //  1.05 MB
    u16* bhi = (u16*)ws;
    u16* blo = (u16*)(ws + BPLANE);
    u16* ahi = (u16*)(ws + 2 * BPLANE);
    u16* alo = (u16*)(ws + 2 * BPLANE + APLANE);
    float* sums = (float*)(ws + 2 * BPLANE + 2 * APLANE);          // 16 KB

    prep_samp<<<dim3(NB * NS / 2), 256, 0, stream>>>(src, loc, ahi, alo, sums);
    prep_tgt<<<dim3(HW / 64, NB), 256, 0, stream>>>(tgt, bhi, blo);

    dim3 g(NPT * NST * NB);   // 768 flat, decoded with XCD swizzle in-kernel
    corr2<0><<<g, 512, 0, stream>>>(bhi, blo, ahi, alo, mask, sums, out);
    corr2<1><<<g, 512, 0, stream>>>(bhi, blo, ahi, alo, mask, sums, out);
}